// Round 1
// baseline (358.020 us; speedup 1.0000x reference)
//
#include <hip/hip_runtime.h>

#define XDIM 159
#define YDIM 191
#define ZDIM 159
#define IXD 160
#define IYD 192
#define IZD 160

#define TS 8     // output tile edge
#define GR 14    // gradient region TS+6
#define IRD 15   // input region TS+7

// LDS float layout:
// [0, 6750): sI [15][15][15] at 0, sJ at 3375; later aliased by s2 (5712 floats)
// [6750, 17334): s1 [6][14][14][9]
#define SJ_OFF 3375
#define S1_OFF 6750
#define S1_F   1764   // 14*14*9
#define S1_LX  126    // 14*9
#define S1_LY  9
#define S2_F   952    // 14*68
#define S2_LX  68     // 68 % 32 == 4 -> 2-way max vs oz stride 1
#define LDS_FLOATS (6750 + 10584)

#define NVOX 9657342.0f   // 2*159*191*159

__global__ __launch_bounds__(256) void grad_sim_kernel(
    const float* __restrict__ Ii, const float* __restrict__ Ji,
    float* __restrict__ out)
{
    __shared__ float lds[LDS_FLOATS];
    const int tid = threadIdx.x;
    const int z0 = blockIdx.x * TS;
    const int y0 = blockIdx.y * TS;
    const int x0 = (blockIdx.z % 20) * TS;
    const int bb = blockIdx.z / 20;

    const float* baseI = Ii + (size_t)bb * (IXD * IYD * IZD);
    const float* baseJ = Ji + (size_t)bb * (IXD * IYD * IZD);

    // ---- stage 0: load input halo tiles ----
    for (int idx = tid; idx < IRD * IRD * IRD; idx += 256) {
        int a = idx / (IRD * IRD);
        int r = idx % (IRD * IRD);
        int b = r / IRD;
        int c = r % IRD;
        int ix = x0 - 3 + a, iy = y0 - 3 + b, iz = z0 - 3 + c;
        bool ok = (unsigned)ix < IXD && (unsigned)iy < IYD && (unsigned)iz < IZD;
        float vi = 0.0f, vj = 0.0f;
        if (ok) {
            size_t g = ((size_t)(ix * IYD + iy)) * IZD + iz;
            vi = baseI[g];
            vj = baseJ[g];
        }
        lds[idx] = vi;
        lds[SJ_OFF + idx] = vj;
    }
    __syncthreads();

    // ---- stage 1: gradient + sliding z-sum -> s1[f][lx][ly][oz] ----
    // tasks: f in [0,6), lx in [0,14), ly in [0,14)
    for (int t = tid; t < 6 * 196; t += 256) {
        int f = t / 196;
        int r = t % 196;
        int lx = r / 14, ly = r % 14;
        bool vx = (unsigned)(x0 - 3 + lx) < XDIM;
        bool vy = (unsigned)(y0 - 3 + ly) < YDIM;
        const float* s = lds + (f >= 3 ? SJ_OFF : 0);
        int axis = f % 3;                        // 0:dx 1:dy 2:dz
        int cb = (lx + 1) * 225 + (ly + 1) * 15; // c = I[g+1 each axis]
        int nb = cb - (axis == 0 ? 225 : 0) - (axis == 1 ? 15 : 0);
        int zn = (axis == 2) ? 0 : 1;            // neighbor z offset

        float g[14];
#pragma unroll
        for (int zz = 0; zz < 14; ++zz) {
            float val = s[cb + zz + 1] - s[nb + zz + zn];
            bool vz = (unsigned)(z0 - 3 + zz) < ZDIM;
            g[zz] = (vx && vy && vz) ? val : 0.0f;
        }
        float w = g[0] + g[1] + g[2] + g[3] + g[4] + g[5] + g[6];
        int ob = S1_OFF + f * S1_F + lx * S1_LX + ly * S1_LY;
        lds[ob] = w;
#pragma unroll
        for (int oz = 1; oz < 8; ++oz) {
            w += g[oz + 6] - g[oz - 1];
            lds[ob + oz] = w;
        }
    }
    __syncthreads();

    // ---- stage 2: sliding y-sum -> s2[f][lx][oy*8+oz] (aliases sI/sJ) ----
    // tasks: f in [0,6), lx in [0,14), oz in [0,8)
    for (int t = tid; t < 6 * 112; t += 256) {
        int f = t / 112;
        int r = t % 112;
        int lx = r / 8, oz = r % 8;
        int ib = S1_OFF + f * S1_F + lx * S1_LX + oz;
        float h[14];
#pragma unroll
        for (int ly = 0; ly < 14; ++ly) h[ly] = lds[ib + ly * S1_LY];
        float w = h[0] + h[1] + h[2] + h[3] + h[4] + h[5] + h[6];
        int ob = f * S2_F + lx * S2_LX + oz;
        lds[ob] = w;
#pragma unroll
        for (int oy = 1; oy < 8; ++oy) {
            w += h[oy + 6] - h[oy - 1];
            lds[ob + oy * 8] = w;
        }
    }
    __syncthreads();

    // ---- stage 3: 7-tap x-sum + combine ----
    float acc = 0.0f;
#pragma unroll
    for (int vv = 0; vv < 2; ++vv) {
        int v = tid + vv * 256;
        int ox = v / 64, oy = (v / 8) % 8, oz = v % 8;
        bool ok = (x0 + ox < XDIM) && (y0 + oy < YDIM) && (z0 + oz < ZDIM);
        float s3[6];
#pragma unroll
        for (int f = 0; f < 6; ++f) {
            int b0 = f * S2_F + oy * 8 + oz;
            float w = 0.0f;
#pragma unroll
            for (int k = 0; k < 7; ++k) w += lds[b0 + (ox + k) * S2_LX];
            s3[f] = w;
        }
        float cross = fabsf(s3[0] * s3[3] + s3[1] * s3[4] + s3[2] * s3[5]) + 0.01f;
        float dI = s3[0] * s3[0] + s3[1] * s3[1] + s3[2] * s3[2] + 0.01f;
        float dJ = s3[3] * s3[3] + s3[4] * s3[4] + s3[5] * s3[5] + 0.01f;
        float val = cross / sqrtf(dI * dJ);
        if (ok) acc += val;
    }

    // ---- reduce: wave shuffle -> LDS -> one atomic per block ----
#pragma unroll
    for (int off = 32; off > 0; off >>= 1) acc += __shfl_down(acc, off, 64);
    __syncthreads();                 // all stage-3 LDS reads done
    if ((tid & 63) == 0) lds[tid >> 6] = acc;
    __syncthreads();
    if (tid == 0) {
        float total = (lds[0] + lds[1] + lds[2] + lds[3]) * (1.0f / NVOX);
        atomicAdd(out, total);
    }
}

extern "C" void kernel_launch(void* const* d_in, const int* in_sizes, int n_in,
                              void* d_out, int out_size, void* d_ws, size_t ws_size,
                              hipStream_t stream) {
    const float* Ii = (const float*)d_in[0];
    const float* Ji = (const float*)d_in[1];
    float* out = (float*)d_out;
    hipMemsetAsync(d_out, 0, sizeof(float) * (out_size > 0 ? out_size : 1), stream);
    dim3 grid(20, 24, 40);   // z-tiles, y-tiles, x-tiles * batch
    grad_sim_kernel<<<grid, dim3(256), 0, stream>>>(Ii, Ji, out);
}

// Round 2
// 289.673 us; speedup vs baseline: 1.2359x; 1.2359x over previous
//
#include <hip/hip_runtime.h>

#define IXD 160
#define IYD 192
#define IZD 160
#define XDIM 159
#define YDIM 191
#define ZDIM 159

// tile 16 x 8 x 8 (x,y,z), 512 threads
// input halo region 23 x 15 x 15, z padded to pitch 20
#define IN_PX 300    // = 15*20
#define IN_PY 20
#define IN_SZ 6900   // = 23*300

#define S1_BASE 6900
#define S1_PX 116    // 14*8 + 4
#define S1_PF 2552   // 22*116
// s1 = [3][22][116] -> 7656 floats, ends at 14556

#define S2I_BASE 14556
#define S2J_BASE 0   // overlays dead input buffer
#define S2_PX 68     // 8*8 + 4
#define S2_PF 1496   // 22*68
// each s2 = [3][22][68] = 4488 floats; s2I ends at 19044

#define S3_BASE 4488
#define S3_PF 1024   // [6][16][64]

#define LDS_FLOATS 19044

#define NVOX_INV (1.0f / 9657342.0f)   // 2*159*191*159

__device__ __forceinline__ void slide_emit(float* lds, const float* d, int ob) {
    float o0, o1, o2, o3, o4, o5, o6, o7;
    float w = d[0] + d[1] + d[2] + d[3] + d[4] + d[5] + d[6];
    o0 = w;
    w += d[7] - d[0];  o1 = w;
    w += d[8] - d[1];  o2 = w;
    w += d[9] - d[2];  o3 = w;
    w += d[10] - d[3]; o4 = w;
    w += d[11] - d[4]; o5 = w;
    w += d[12] - d[5]; o6 = w;
    w += d[13] - d[6]; o7 = w;
    *(float4*)&lds[ob]     = make_float4(o0, o1, o2, o3);
    *(float4*)&lds[ob + 4] = make_float4(o4, o5, o6, o7);
}

__device__ __forceinline__ void process_volume(float* lds, const float* __restrict__ gsrc,
                                               int s2base, int tid,
                                               int x0, int y0, int z0)
{
    // ---- stage 0: load 23x15x15 halo (z pitch 20) ----
    for (int idx = tid; idx < 23 * 225; idx += 512) {
        int a = idx / 225;
        int r = idx % 225;
        int b = r / 15;
        int c = r % 15;
        int ix = x0 - 3 + a, iy = y0 - 3 + b, iz = z0 - 3 + c;
        float v = 0.0f;
        if ((unsigned)ix < IXD && (unsigned)iy < IYD && (unsigned)iz < IZD)
            v = gsrc[((size_t)(ix * IYD + iy)) * IZD + iz];
        lds[a * IN_PX + b * IN_PY + c] = v;
    }
    __syncthreads();

    // ---- stage 1: 3 gradients + sliding z-sum -> s1[f][lx][ly*8+oz] ----
    if (tid < 308) {
        int lx = tid / 14, ly = tid % 14;
        bool vx = (unsigned)(x0 - 3 + lx) < XDIM;
        bool vy = (unsigned)(y0 - 3 + ly) < YDIM;
        float A[16], B[16], C[16];
        const float4* pA = (const float4*)&lds[(lx + 1) * IN_PX + (ly + 1) * IN_PY];
        const float4* pB = (const float4*)&lds[lx * IN_PX + (ly + 1) * IN_PY];
        const float4* pC = (const float4*)&lds[(lx + 1) * IN_PX + ly * IN_PY];
#pragma unroll
        for (int q = 0; q < 4; ++q) {
            ((float4*)A)[q] = pA[q];
            ((float4*)B)[q] = pB[q];
            ((float4*)C)[q] = pC[q];
        }
        float m[14];
#pragma unroll
        for (int zz = 0; zz < 14; ++zz)
            m[zz] = (vx && vy && ((unsigned)(z0 - 3 + zz) < ZDIM)) ? 1.0f : 0.0f;

        int ob = S1_BASE + lx * S1_PX + ly * 8;
        float d[14];
#pragma unroll
        for (int zz = 0; zz < 14; ++zz) d[zz] = (A[zz + 1] - B[zz + 1]) * m[zz]; // dx
        slide_emit(lds, d, ob);
#pragma unroll
        for (int zz = 0; zz < 14; ++zz) d[zz] = (A[zz + 1] - C[zz + 1]) * m[zz]; // dy
        slide_emit(lds, d, ob + S1_PF);
#pragma unroll
        for (int zz = 0; zz < 14; ++zz) d[zz] = (A[zz + 1] - A[zz]) * m[zz];     // dz
        slide_emit(lds, d, ob + 2 * S1_PF);
    }
    __syncthreads();

    // ---- stage 2: sliding y-sum -> s2[f][lx][oy*8+oz] ----
    for (int t = tid; t < 528; t += 512) {
        int f = t / 176;          // 22*8
        int r = t % 176;
        int lx = r / 8, oz = r % 8;
        int ib = S1_BASE + f * S1_PF + lx * S1_PX + oz;
        float h[14];
#pragma unroll
        for (int ly = 0; ly < 14; ++ly) h[ly] = lds[ib + ly * 8];
        int obase = s2base + f * S2_PF + lx * S2_PX + oz;
        float w = h[0] + h[1] + h[2] + h[3] + h[4] + h[5] + h[6];
        lds[obase] = w;
#pragma unroll
        for (int oy = 1; oy < 8; ++oy) {
            w += h[oy + 6] - h[oy - 1];
            lds[obase + oy * 8] = w;
        }
    }
    __syncthreads();
}

__global__ __launch_bounds__(512, 4) void grad_sim_kernel(
    const float* __restrict__ Ii, const float* __restrict__ Ji,
    float* __restrict__ out)
{
    __shared__ float lds[LDS_FLOATS];
    const int tid = threadIdx.x;
    const int z0 = blockIdx.x * 8;
    const int y0 = blockIdx.y * 8;
    const int x0 = (blockIdx.z % 10) * 16;
    const int bb = blockIdx.z / 10;

    const float* baseI = Ii + (size_t)bb * (IXD * IYD * IZD);
    const float* baseJ = Ji + (size_t)bb * (IXD * IYD * IZD);

    process_volume(lds, baseI, S2I_BASE, tid, x0, y0, z0);
    process_volume(lds, baseJ, S2J_BASE, tid, x0, y0, z0);

    // ---- stage 3a: sliding x-sum per (field, column) -> s3[f][ox][col] ----
    if (tid < 384) {
        int f = tid >> 6;          // 0..5
        int col = tid & 63;        // oy*8+oz
        int ib = (f < 3 ? S2I_BASE + f * S2_PF : S2J_BASE + (f - 3) * S2_PF) + col;
        float u[22];
#pragma unroll
        for (int lx = 0; lx < 22; ++lx) u[lx] = lds[ib + lx * S2_PX];
        int obase = S3_BASE + f * S3_PF + col;
        float w = u[0] + u[1] + u[2] + u[3] + u[4] + u[5] + u[6];
        lds[obase] = w;
#pragma unroll
        for (int ox = 1; ox < 16; ++ox) {
            w += u[ox + 6] - u[ox - 1];
            lds[obase + ox * 64] = w;
        }
    }
    __syncthreads();

    // ---- stage 3b: combine + reduce ----
    float acc = 0.0f;
#pragma unroll
    for (int vv = 0; vv < 2; ++vv) {
        int v = tid + vv * 512;
        int ox = v >> 6;
        int col = v & 63;
        int oy = col >> 3, oz = col & 7;
        bool ok = (x0 + ox < XDIM) && (y0 + oy < YDIM) && (z0 + oz < ZDIM);
        float s0 = lds[S3_BASE + 0 * S3_PF + v];
        float s1 = lds[S3_BASE + 1 * S3_PF + v];
        float s2 = lds[S3_BASE + 2 * S3_PF + v];
        float s3 = lds[S3_BASE + 3 * S3_PF + v];
        float s4 = lds[S3_BASE + 4 * S3_PF + v];
        float s5 = lds[S3_BASE + 5 * S3_PF + v];
        float cross = fabsf(s0 * s3 + s1 * s4 + s2 * s5) + 0.01f;
        float dI = s0 * s0 + s1 * s1 + s2 * s2 + 0.01f;
        float dJ = s3 * s3 + s4 * s4 + s5 * s5 + 0.01f;
        float val = cross / sqrtf(dI * dJ);
        if (ok) acc += val;
    }

#pragma unroll
    for (int off = 32; off > 0; off >>= 1) acc += __shfl_down(acc, off, 64);
    __syncthreads();   // all stage-3 LDS reads complete before reuse
    if ((tid & 63) == 0) lds[tid >> 6] = acc;
    __syncthreads();
    if (tid == 0) {
        float total = 0.0f;
#pragma unroll
        for (int wv = 0; wv < 8; ++wv) total += lds[wv];
        atomicAdd(out, total * NVOX_INV);
    }
}

extern "C" void kernel_launch(void* const* d_in, const int* in_sizes, int n_in,
                              void* d_out, int out_size, void* d_ws, size_t ws_size,
                              hipStream_t stream) {
    const float* Ii = (const float*)d_in[0];
    const float* Ji = (const float*)d_in[1];
    float* out = (float*)d_out;
    hipMemsetAsync(d_out, 0, sizeof(float) * (out_size > 0 ? out_size : 1), stream);
    dim3 grid(20, 24, 20);   // z-tiles, y-tiles, x-tiles(10) * batch(2)
    grad_sim_kernel<<<grid, dim3(512), 0, stream>>>(Ii, Ji, out);
}

// Round 3
// 136.669 us; speedup vs baseline: 2.6196x; 2.1195x over previous
//
#include <hip/hip_runtime.h>

#define IYD 192
#define IZD 160
#define PLANE 30720        // IYD*IZD
#define VOLSZ 4915200      // 160*PLANE
#define YG 191
#define ZG 159
#define XG 159

// LDS float layout (28.1 KB total):
// inP[2 vol][2 parity][15 y][44 zpitch] = 2640
// s1[6 f][14 ly][36 zpitch]             = 3024 @ 2640
// Hp[6 f][8 oy][32 oz]                  = 1536 @ 5664
#define INP_V 1320
#define INP_P 660
#define INP_Y 44
#define S1B 2640
#define S1F 504
#define S1Y 36
#define HPB 5664
#define LDSF 7200

#define NVOX_INV (1.0f / 9657342.0f)   // 2*159*191*159

__device__ __forceinline__ void slide14_store(float* lds, const float* d, int ob) {
    float o[8];
    o[0] = d[0] + d[1] + d[2] + d[3] + d[4] + d[5] + d[6];
#pragma unroll
    for (int m = 1; m < 8; ++m) o[m] = o[m - 1] + d[m + 6] - d[m - 1];
    *(float4*)&lds[ob]     = make_float4(o[0], o[1], o[2], o[3]);
    *(float4*)&lds[ob + 4] = make_float4(o[4], o[5], o[6], o[7]);
}

__global__ __launch_bounds__(256, 3) void grad_sim_stream(
    const float* __restrict__ Ii, const float* __restrict__ Ji,
    float* __restrict__ out)
{
    __shared__ __align__(16) float lds[LDSF];
    const int tid = threadIdx.x;
    const int z0 = (int)blockIdx.x * 32;
    const int y0 = (int)blockIdx.y * 8;
    const int seg = blockIdx.z & 3;
    const int bat = blockIdx.z >> 2;
    const int s0 = seg * 40;
    const int s1e = (seg == 3) ? XG : (s0 + 40);

    const float* __restrict__ bI = Ii + (size_t)bat * VOLSZ;
    const float* __restrict__ bJ = Ji + (size_t)bat * VOLSZ;

    // ---- precompute load slots (plane-relative): 2 vols x 15 y x 39 z = 1170 ----
    const float* gp[5];
    int lof[5];
    bool okl[5];
#pragma unroll
    for (int k = 0; k < 5; ++k) {
        int idx = tid + 256 * k;
        bool inr = idx < 1170;
        int id2 = inr ? idx : 0;
        int v = id2 / 585;
        int r = id2 - v * 585;
        int yy = r / 39;
        int zz = r - yy * 39;
        int iy = y0 - 3 + yy;
        int iz = z0 - 3 + zz;
        bool ok = inr && ((unsigned)iy < IYD) && ((unsigned)iz < IZD);
        int iyc = min(max(iy, 0), IYD - 1);
        int izc = min(max(iz, 0), IZD - 1);
        gp[k] = (v ? bJ : bI) + (iyc * IZD + izc);
        lof[k] = v * INP_V + yy * INP_Y + zz;
        okl[k] = ok;
    }

    // stage-1 task decode: (vol, ly in 0..13, zquad in 0..3) -> 112 lanes
    const int t1v  = tid / 56;
    const int t1r  = tid - t1v * 56;
    const int t1ly = t1r >> 2;
    const int t1q  = t1r & 3;
    const bool do1 = tid < 112;
    // stage-2: (f in 0..5, oz in 0..31) -> 192 lanes
    const int t2f = tid >> 5;
    const int t2z = tid & 31;
    const bool do2 = tid < 192;
    // stage-3 output validity for this thread's (oy,oz) column
    const bool okyz = ((y0 + (tid >> 5)) < YG) && ((z0 + (tid & 31)) < ZG);

    // x-window register ring (all indices compile-time constant)
    float R[7][6], S[6], acc = 0.f;
#pragma unroll
    for (int j = 0; j < 7; ++j)
#pragma unroll
        for (int f = 0; f < 6; ++f) R[j][f] = 0.f;
#pragma unroll
    for (int f = 0; f < 6; ++f) S[f] = 0.f;

    const int a0 = max(s0 - 3, 0);
    const int aMainEnd = min(s1e + 3, XG);

    // prologue: plane a0 -> parity a0&1
    {
        const int pb = a0 * PLANE;
        const int po = (a0 & 1) * INP_P;
#pragma unroll
        for (int k = 0; k < 5; ++k) {
            float v = gp[k][pb];
            lds[lof[k] + po] = okl[k] ? v : 0.f;
        }
    }

    int a = a0;
    for (; a < aMainEnd; ++a) {
        // ---- load plane a+1 -> parity (a+1)&1 ----
        {
            const int pb = (a + 1) * PLANE;
            const int po = ((a + 1) & 1) * INP_P;
#pragma unroll
            for (int k = 0; k < 5; ++k) {
                float v = gp[k][pb];
                lds[lof[k] + po] = okl[k] ? v : 0.f;
            }
        }
        __syncthreads();

        // ---- stage 1: gradients + z-slide -> s1[f][ly][oz] ----
        if (do1) {
            const int parC = (a + 1) & 1;
            const int parP = a & 1;
            const float* baseC = &lds[t1v * INP_V + parC * INP_P + (t1ly + 1) * INP_Y + 8 * t1q];
            const float* baseP = &lds[t1v * INP_V + parP * INP_P + (t1ly + 1) * INP_Y + 8 * t1q];
            const float* baseY = &lds[t1v * INP_V + parC * INP_P + t1ly * INP_Y + 8 * t1q];
            float C[16], N[16], d[14];
#pragma unroll
            for (int u = 0; u < 4; ++u) ((float4*)C)[u] = ((const float4*)baseC)[u];
            const bool my = (unsigned)(y0 - 3 + t1ly) < YG;
            const int gz0 = z0 - 3 + 8 * t1q;
            float mk[14];
#pragma unroll
            for (int i = 0; i < 14; ++i)
                mk[i] = (my && ((unsigned)(gz0 + i) < ZG)) ? 1.f : 0.f;
            const int ob = S1B + (3 * t1v) * S1F + t1ly * S1Y + 8 * t1q;
            // dx = cur[y+1][z+1] - prev[y+1][z+1]
#pragma unroll
            for (int u = 0; u < 4; ++u) ((float4*)N)[u] = ((const float4*)baseP)[u];
#pragma unroll
            for (int i = 0; i < 14; ++i) d[i] = (C[i + 1] - N[i + 1]) * mk[i];
            slide14_store(lds, d, ob);
            // dy = cur[y+1][z+1] - cur[y][z+1]
#pragma unroll
            for (int u = 0; u < 4; ++u) ((float4*)N)[u] = ((const float4*)baseY)[u];
#pragma unroll
            for (int i = 0; i < 14; ++i) d[i] = (C[i + 1] - N[i + 1]) * mk[i];
            slide14_store(lds, d, ob + S1F);
            // dz = cur[y+1][z+1] - cur[y+1][z]
#pragma unroll
            for (int i = 0; i < 14; ++i) d[i] = (C[i + 1] - C[i]) * mk[i];
            slide14_store(lds, d, ob + 2 * S1F);
        }
        __syncthreads();

        // ---- stage 2: y-slide -> Hp[f][oy][oz] ----
        if (do2) {
            const int ib = S1B + t2f * S1F + t2z;
            float h[14];
#pragma unroll
            for (int l = 0; l < 14; ++l) h[l] = lds[ib + l * S1Y];
            const int oh = HPB + t2f * 256 + t2z;
            float w = h[0] + h[1] + h[2] + h[3] + h[4] + h[5] + h[6];
            lds[oh] = w;
#pragma unroll
            for (int oy = 1; oy < 8; ++oy) {
                w += h[oy + 6] - h[oy - 1];
                lds[oh + oy * 32] = w;
            }
        }
        __syncthreads();

        // ---- stage 3: per-thread x ring + emit ox = a-3 ----
        float h[6];
#pragma unroll
        for (int f = 0; f < 6; ++f) h[f] = lds[HPB + f * 256 + tid];
#pragma unroll
        for (int f = 0; f < 6; ++f) S[f] += h[f] - R[6][f];
#pragma unroll
        for (int j = 6; j >= 1; --j)
#pragma unroll
            for (int f = 0; f < 6; ++f) R[j][f] = R[j - 1][f];
#pragma unroll
        for (int f = 0; f < 6; ++f) R[0][f] = h[f];
        if (a >= s0 + 3) {
            float cross = fabsf(S[0] * S[3] + S[1] * S[4] + S[2] * S[5]) + 0.01f;
            float dI = S[0] * S[0] + S[1] * S[1] + S[2] * S[2] + 0.01f;
            float dJ = S[3] * S[3] + S[4] * S[4] + S[5] * S[5] + 0.01f;
            float val = cross / sqrtf(dI * dJ);
            if (okyz) acc += val;
        }
    }

    // ---- tail: zero-H pushes past x=158 (last segment only) ----
    for (; a < s1e + 3; ++a) {
#pragma unroll
        for (int f = 0; f < 6; ++f) S[f] -= R[6][f];
#pragma unroll
        for (int j = 6; j >= 1; --j)
#pragma unroll
            for (int f = 0; f < 6; ++f) R[j][f] = R[j - 1][f];
#pragma unroll
        for (int f = 0; f < 6; ++f) R[0][f] = 0.f;
        float cross = fabsf(S[0] * S[3] + S[1] * S[4] + S[2] * S[5]) + 0.01f;
        float dI = S[0] * S[0] + S[1] * S[1] + S[2] * S[2] + 0.01f;
        float dJ = S[3] * S[3] + S[4] * S[4] + S[5] * S[5] + 0.01f;
        float val = cross / sqrtf(dI * dJ);
        if (okyz) acc += val;
    }

    // ---- block reduce + atomic ----
#pragma unroll
    for (int off = 32; off > 0; off >>= 1) acc += __shfl_down(acc, off, 64);
    __syncthreads();
    if ((tid & 63) == 0) lds[tid >> 6] = acc;
    __syncthreads();
    if (tid == 0)
        atomicAdd(out, (lds[0] + lds[1] + lds[2] + lds[3]) * NVOX_INV);
}

extern "C" void kernel_launch(void* const* d_in, const int* in_sizes, int n_in,
                              void* d_out, int out_size, void* d_ws, size_t ws_size,
                              hipStream_t stream) {
    const float* Ii = (const float*)d_in[0];
    const float* Ji = (const float*)d_in[1];
    float* out = (float*)d_out;
    hipMemsetAsync(d_out, 0, sizeof(float) * (out_size > 0 ? out_size : 1), stream);
    dim3 grid(5, 24, 8);   // z-tiles(32) x y-tiles(8) x (4 x-segments * 2 batches)
    grad_sim_stream<<<grid, dim3(256), 0, stream>>>(Ii, Ji, out);
}

// Round 4
// 106.557 us; speedup vs baseline: 3.3599x; 1.2826x over previous
//
#include <hip/hip_runtime.h>

#define IYD 192
#define IZD 160
#define PLANE 30720        // IYD*IZD
#define VOLSZ 4915200      // 160*PLANE
#define YG 191
#define ZG 159
#define XG 159

// LDS float layout (8184 floats = 32736 B -> rounds to 32768 -> 5 blocks/CU):
// inP[2 vol][3 slot][15 rows], row r at offset r*40 + 4*(r&1), z 0..38 used
//   slot = 604 floats, vol stride 1812; dump word 600..603 per slot
// s1[6 f][14 ly][36]  @ 3624
// Hp[6 f][8 oy][32 oz] @ 6648
#define SLOT 604
#define VOLO 1812
#define DUMP 600
#define S1B 3624
#define S1F 504
#define S1Y 36
#define HPB 6648
#define LDSF 8184

#define NVOX_INV (1.0f / 9657342.0f)   // 2*159*191*159

__device__ __forceinline__ int rowoff(int r) { return r * 40 + ((r & 1) << 2); }

__device__ __forceinline__ void slide14_store(float* lds, const float* d, int ob) {
    float o[8];
    o[0] = d[0] + d[1] + d[2] + d[3] + d[4] + d[5] + d[6];
#pragma unroll
    for (int m = 1; m < 8; ++m) o[m] = o[m - 1] + d[m + 6] - d[m - 1];
    *(float4*)&lds[ob]     = make_float4(o[0], o[1], o[2], o[3]);
    *(float4*)&lds[ob + 4] = make_float4(o[4], o[5], o[6], o[7]);
}

__global__ __launch_bounds__(256, 4) void grad_sim_stream(
    const float* __restrict__ Ii, const float* __restrict__ Ji,
    float* __restrict__ out)
{
    __shared__ __align__(16) float lds[LDSF];
    const int tid = threadIdx.x;
    const int z0 = (int)blockIdx.x * 32;
    const int y0 = (int)blockIdx.y * 8;
    const int seg = blockIdx.z & 7;
    const int bat = blockIdx.z >> 3;
    const int s0 = seg * 20;
    const int s1e = (seg == 7) ? XG : (s0 + 20);

    const float* __restrict__ bI = Ii + (size_t)bat * VOLSZ;
    const float* __restrict__ bJ = Ji + (size_t)bat * VOLSZ;

    // ---- per-thread load slots: 2 vols x 15 y x 39 z = 1170 lanes ----
    const float* gp[5];
    int lof[5];
    bool okl[5];
#pragma unroll
    for (int k = 0; k < 5; ++k) {
        int idx = tid + 256 * k;
        bool inr = idx < 1170;
        int id2 = inr ? idx : 0;
        int v = id2 / 585;
        int r = id2 - v * 585;
        int yy = r / 39;
        int zz = r - yy * 39;
        int iy = y0 - 3 + yy;
        int iz = z0 - 3 + zz;
        okl[k] = inr && ((unsigned)iy < IYD) && ((unsigned)iz < IZD);
        int iyc = min(max(iy, 0), IYD - 1);
        int izc = min(max(iz, 0), IZD - 1);
        gp[k] = (v ? bJ : bI) + (iyc * IZD + izc);
        lof[k] = inr ? (v * VOLO + rowoff(yy) + zz) : DUMP;  // DUMP: no write race
    }

    // ---- stage-1 decode (112 lanes): (vol, ly 0..13, zquad 0..3) ----
    const int t1v = tid / 56;
    const int t1r = tid - 56 * t1v;
    const int t1ly = t1r >> 2;
    const int t1q = t1r & 3;
    const bool do1 = tid < 112;
    float mk[14];
    {
        const bool my = (unsigned)(y0 - 3 + t1ly) < YG;
        const int gz0 = z0 - 3 + 8 * t1q;
#pragma unroll
        for (int i = 0; i < 14; ++i)
            mk[i] = (my && ((unsigned)(gz0 + i) < ZG)) ? 1.f : 0.f;
    }
    const int rowC = t1v * VOLO + rowoff(t1ly + 1) + 8 * t1q;
    const int rowY = t1v * VOLO + rowoff(t1ly) + 8 * t1q;
    const int obS1 = S1B + 3 * t1v * S1F + t1ly * S1Y + 8 * t1q;

    // ---- stage-2 decode (192 lanes): (f 0..5, oz 0..31) ----
    const bool do2 = tid < 192;
    const int ibS2 = S1B + (tid >> 5) * S1F + (tid & 31);
    const int ohS2 = HPB + (tid >> 5) * 256 + (tid & 31);

    const bool okyz = ((y0 + (tid >> 5)) < YG) && ((z0 + (tid & 31)) < ZG);

    // x-window register ring (static indices only)
    float R[7][6], S[6], acc = 0.f;
#pragma unroll
    for (int j = 0; j < 7; ++j)
#pragma unroll
        for (int f = 0; f < 6; ++f) R[j][f] = 0.f;
#pragma unroll
    for (int f = 0; f < 6; ++f) S[f] = 0.f;

    const int a0 = max(s0 - 3, 0);
    const int aEnd = min(s1e + 3, XG);

    int oA = (a0 % 3) * SLOT;            // slot of plane a
    int oB = ((a0 + 1) % 3) * SLOT;      // slot of plane a+1
    int oC = ((a0 + 2) % 3) * SLOT;      // slot being filled (plane a+2)

    // ---- prologue: planes a0, a0+1 -> LDS ----
    {
        const int pbA = a0 * PLANE, pbB = (a0 + 1) * PLANE;
        float rA[5], rB[5];
#pragma unroll
        for (int k = 0; k < 5; ++k) rA[k] = gp[k][pbA];
#pragma unroll
        for (int k = 0; k < 5; ++k) rB[k] = gp[k][pbB];
#pragma unroll
        for (int k = 0; k < 5; ++k) lds[oA + lof[k]] = okl[k] ? rA[k] : 0.f;
#pragma unroll
        for (int k = 0; k < 5; ++k) lds[oB + lof[k]] = okl[k] ? rB[k] : 0.f;
    }
    __syncthreads();

    for (int a = a0; a < aEnd; ++a) {
        // issue prefetch of plane a+2 (lands at bottom of this step)
        const bool dof = (a + 2) <= aEnd;
        float pf[5];
        if (dof) {
            const int pb = (a + 2) * PLANE;
#pragma unroll
            for (int k = 0; k < 5; ++k) pf[k] = gp[k][pb];
        }

        // ---- stage 1: gradient plane a (C = slot oB, P = slot oA) ----
        if (do1) {
            const float* pC = &lds[rowC + oB];
            const float* pP = &lds[rowC + oA];
            const float* pY = &lds[rowY + oB];
            float C[16], N[16], d[14];
#pragma unroll
            for (int u = 0; u < 4; ++u) ((float4*)C)[u] = ((const float4*)pC)[u];
            // dz (C only)
#pragma unroll
            for (int i = 0; i < 14; ++i) d[i] = (C[i + 1] - C[i]) * mk[i];
            slide14_store(lds, d, obS1 + 2 * S1F);
            // dy
#pragma unroll
            for (int u = 0; u < 4; ++u) ((float4*)N)[u] = ((const float4*)pY)[u];
#pragma unroll
            for (int i = 0; i < 14; ++i) d[i] = (C[i + 1] - N[i + 1]) * mk[i];
            slide14_store(lds, d, obS1 + S1F);
            // dx
#pragma unroll
            for (int u = 0; u < 4; ++u) ((float4*)N)[u] = ((const float4*)pP)[u];
#pragma unroll
            for (int i = 0; i < 14; ++i) d[i] = (C[i + 1] - N[i + 1]) * mk[i];
            slide14_store(lds, d, obS1);
        }
        __syncthreads();

        // ---- stage 2: y-slide -> Hp ----
        if (do2) {
            float h[14];
#pragma unroll
            for (int l = 0; l < 14; ++l) h[l] = lds[ibS2 + l * S1Y];
            float w = h[0] + h[1] + h[2] + h[3] + h[4] + h[5] + h[6];
            lds[ohS2] = w;
#pragma unroll
            for (int oy = 1; oy < 8; ++oy) {
                w += h[oy + 6] - h[oy - 1];
                lds[ohS2 + oy * 32] = w;
            }
        }
        __syncthreads();

        // ---- stage 3: x ring push + emit ox = a-3 ----
        {
            float h[6];
#pragma unroll
            for (int f = 0; f < 6; ++f) h[f] = lds[HPB + f * 256 + tid];
#pragma unroll
            for (int f = 0; f < 6; ++f) S[f] += h[f] - R[6][f];
#pragma unroll
            for (int j = 6; j >= 1; --j)
#pragma unroll
                for (int f = 0; f < 6; ++f) R[j][f] = R[j - 1][f];
#pragma unroll
            for (int f = 0; f < 6; ++f) R[0][f] = h[f];
            if (a >= s0 + 3) {
                float cross = fabsf(S[0] * S[3] + S[1] * S[4] + S[2] * S[5]) + 0.01f;
                float dI = S[0] * S[0] + S[1] * S[1] + S[2] * S[2] + 0.01f;
                float dJ = S[3] * S[3] + S[4] * S[4] + S[5] * S[5] + 0.01f;
                float val = cross / sqrtf(dI * dJ);
                if (okyz) acc += val;
            }
        }

        // ---- land prefetch into slot oC (no alias with oA/oB) ----
        if (dof) {
#pragma unroll
            for (int k = 0; k < 5; ++k) lds[oC + lof[k]] = okl[k] ? pf[k] : 0.f;
        }
        __syncthreads();
        int t = oA; oA = oB; oB = oC; oC = t;
    }

    // ---- tail: zero pushes (last x-segment only) ----
    for (int a = aEnd; a < s1e + 3; ++a) {
#pragma unroll
        for (int f = 0; f < 6; ++f) S[f] -= R[6][f];
#pragma unroll
        for (int j = 6; j >= 1; --j)
#pragma unroll
            for (int f = 0; f < 6; ++f) R[j][f] = R[j - 1][f];
#pragma unroll
        for (int f = 0; f < 6; ++f) R[0][f] = 0.f;
        float cross = fabsf(S[0] * S[3] + S[1] * S[4] + S[2] * S[5]) + 0.01f;
        float dI = S[0] * S[0] + S[1] * S[1] + S[2] * S[2] + 0.01f;
        float dJ = S[3] * S[3] + S[4] * S[4] + S[5] * S[5] + 0.01f;
        float val = cross / sqrtf(dI * dJ);
        if (okyz) acc += val;
    }

    // ---- block reduce + atomic ----
#pragma unroll
    for (int off = 32; off > 0; off >>= 1) acc += __shfl_down(acc, off, 64);
    __syncthreads();
    if ((tid & 63) == 0) lds[tid >> 6] = acc;
    __syncthreads();
    if (tid == 0)
        atomicAdd(out, (lds[0] + lds[1] + lds[2] + lds[3]) * NVOX_INV);
}

extern "C" void kernel_launch(void* const* d_in, const int* in_sizes, int n_in,
                              void* d_out, int out_size, void* d_ws, size_t ws_size,
                              hipStream_t stream) {
    const float* Ii = (const float*)d_in[0];
    const float* Ji = (const float*)d_in[1];
    float* out = (float*)d_out;
    hipMemsetAsync(d_out, 0, sizeof(float) * (out_size > 0 ? out_size : 1), stream);
    dim3 grid(5, 24, 16);   // z-tiles(32) x y-tiles(8) x (8 x-segments * 2 batches)
    grad_sim_stream<<<grid, dim3(256), 0, stream>>>(Ii, Ji, out);
}

// Round 5
// 86.215 us; speedup vs baseline: 4.1527x; 1.2360x over previous
//
#include <hip/hip_runtime.h>

#define IYD 192
#define IZD 160
#define PLANE 30720        // IYD*IZD
#define VOLSZ 4915200      // 160*PLANE
#define YG 191
#define ZG 159

// LDS float layout (4504 floats = 17.6 KB):
// RAW  @0    : [2v][15r][44]  raw plane (z idx 0..38 used, pitch 44)
// ZB   @1320 : [2v][15r][36]  Zrow = masked z-box of raw (32 used)
// DB   @2400 : [2v][15r][36]  D = raw[z+4]-raw[z-3] (clamped)
// TB   @3480 : [2v][8][32]    Tp = masked y-box of Zrow
// WB   @3992 : [2v][8][32]    Wp = masked y-box of D
#define RAW_V 660
#define RAW_R 44
#define ZB 1320
#define DB 2400
#define ZD_V 540
#define ZD_R 36
#define TB 3480
#define WB 3992
#define LDSF 4504

#define NVOX_INV (1.0f / 9657342.0f)   // 2*159*191*159

__global__ __launch_bounds__(256, 4) void grad_sim_tele(
    const float* __restrict__ Ii, const float* __restrict__ Ji,
    float* __restrict__ out)
{
    __shared__ __align__(16) float lds[LDSF];
    const int tid = threadIdx.x;
    const int z0 = (int)blockIdx.x * 32;
    const int y0 = (int)blockIdx.y * 8;
    const int seg = blockIdx.z & 7;
    const int bat = blockIdx.z >> 3;
    const int s0 = seg * 20;
    const int a0 = (seg == 0) ? 0 : (s0 - 3);
    const int aLast = (seg == 7) ? 159 : (s0 + 23);

    const float* __restrict__ bI = Ii + (size_t)bat * VOLSZ;
    const float* __restrict__ bJ = Ji + (size_t)bat * VOLSZ;

    // ---- per-thread halo-load slots: 2 vols x 15 rows x 39 z = 1170 ----
    const float* gp[5];
    int lof[5];
    bool okl[5];
#pragma unroll
    for (int k = 0; k < 5; ++k) {
        int idx = tid + 256 * k;
        bool inr = idx < 1170;
        int id2 = inr ? idx : 0;
        int v = id2 / 585;
        int r = id2 - v * 585;
        int yy = r / 39;
        int zz = r - yy * 39;
        int iy = y0 - 3 + yy;
        int iz = z0 - 3 + zz;
        okl[k] = inr && ((unsigned)iy < IYD) && ((unsigned)iz < IZD);
        int iyc = min(max(iy, 0), IYD - 1);
        int izc = min(max(iz, 0), IZD - 1);
        gp[k] = (v ? bJ : bI) + (iyc * IZD + izc);
        lof[k] = inr ? (v * RAW_V + yy * RAW_R + zz) : 43;  // 43 = dump word
    }

    // ---- stage-Z decode (120 lanes): (vol, row 0..14, quad 0..3) ----
    const int zv = tid / 60;
    const int zrr = tid - 60 * zv;
    const int zr = zrr >> 2;
    const int zq = zrr & 3;
    const bool doZ = tid < 120;
    const bool zlo = (z0 == 0) && (zq == 0);
    const bool zhi = (z0 == 128) && (zq == 3);
    const int rawRd = zv * RAW_V + zr * RAW_R + 8 * zq;
    const int zdWr = zv * ZD_V + zr * ZD_R + 8 * zq;

    // ---- stage-Y decode (128 lanes): (field 0..3 = T_I,T_J,W_I,W_J, oz) ----
    const bool doY = tid < 128;
    const int yf = tid >> 5;
    const int yv = yf & 1;
    const int yisW = yf >> 1;
    const int ybase = (yisW ? DB : ZB) + yv * ZD_V + (tid & 31);
    const int yout = (yisW ? WB : TB) + yv * 256 + (tid & 31);

    // ---- YX per-thread column ----
    const int oy = tid >> 5;
    const int oz = tid & 31;
    const int ygl = y0 + oy;
    const int vmax = min(3, 190 - ygl);
    const int vmin = max(-3, -ygl);
    const int relHi = oy + vmax + 4;
    const int relLo = oy + vmin + 3;
    const int vHiI = ZB + relHi * ZD_R + oz;
    const int vLoI = ZB + relLo * ZD_R + oz;
    const bool okyz = (ygl < YG) && ((z0 + oz) < ZG);

    // rings (all indices compile-time after unroll)
    float Tr[2][8], Vr[2][8], Wr[2][8], Sdy[2], Sdz[2];
#pragma unroll
    for (int v = 0; v < 2; ++v) {
#pragma unroll
        for (int j = 0; j < 8; ++j) { Tr[v][j] = 0.f; Vr[v][j] = 0.f; Wr[v][j] = 0.f; }
        Sdy[v] = 0.f; Sdz[v] = 0.f;
    }
    float acc = 0.f;

    // ---- prologue: land raw plane a0 ----
    {
        const int pb = a0 * PLANE;
        float t[5];
#pragma unroll
        for (int k = 0; k < 5; ++k) t[k] = gp[k][pb];
#pragma unroll
        for (int k = 0; k < 5; ++k) lds[lof[k]] = okl[k] ? t[k] : 0.f;
    }
    __syncthreads();

    for (int ag = (a0 & ~7); ag <= aLast; ag += 8) {
#pragma unroll
        for (int p = 0; p < 8; ++p) {
            const int a = ag + p;
            if (a < a0 || a > aLast) continue;   // uniform

            // ---- E1: issue prefetch of plane a+1; stage Z on plane a ----
            const bool dof = (a + 1) <= aLast;
            float pf[5];
            if (dof) {
                const int pb = (a + 1) * PLANE;
#pragma unroll
                for (int k = 0; k < 5; ++k) pf[k] = gp[k][pb];
            }
            if (doZ) {
                float C[16];
                const float4* rb = (const float4*)&lds[rawRd];
#pragma unroll
                for (int u = 0; u < 4; ++u) ((float4*)C)[u] = rb[u];
                float D[8];
#pragma unroll
                for (int i = 0; i < 8; ++i) D[i] = C[i + 7] - C[i];
                if (zlo) { D[0] = C[7] - C[3]; D[1] = C[8] - C[3]; D[2] = C[9] - C[3]; }
                if (zhi) { D[4] = C[10] - C[4]; D[5] = C[10] - C[5];
                           D[6] = C[10] - C[6]; D[7] = C[10] - C[7]; }
                if (zlo) { C[1] = 0.f; C[2] = 0.f; C[3] = 0.f; }
                if (zhi) { C[11] = 0.f; C[12] = 0.f; C[13] = 0.f; C[14] = 0.f; }
                float Z[8];
                float w = C[1] + C[2] + C[3] + C[4] + C[5] + C[6] + C[7];
                Z[0] = w;
#pragma unroll
                for (int m = 1; m < 8; ++m) { w += C[m + 7] - C[m]; Z[m] = w; }
                float4* zb = (float4*)&lds[ZB + zdWr];
                zb[0] = make_float4(Z[0], Z[1], Z[2], Z[3]);
                zb[1] = make_float4(Z[4], Z[5], Z[6], Z[7]);
                float4* db = (float4*)&lds[DB + zdWr];
                db[0] = make_float4(D[0], D[1], D[2], D[3]);
                db[1] = make_float4(D[4], D[5], D[6], D[7]);
            }
            __syncthreads();

            // ---- E2: stage Y (masked y-box slides of Zrow and D) ----
            if (doY) {
                float h[15];
#pragma unroll
                for (int r = 1; r < 15; ++r) h[r] = lds[ybase + r * ZD_R];
                if (y0 == 0)   { h[1] = 0.f; h[2] = 0.f; h[3] = 0.f; }
                if (y0 == 184) { h[11] = 0.f; h[12] = 0.f; h[13] = 0.f; h[14] = 0.f; }
                float w = h[1] + h[2] + h[3] + h[4] + h[5] + h[6] + h[7];
                lds[yout] = w;
#pragma unroll
                for (int q = 1; q < 8; ++q) {
                    w += h[q + 7] - h[q];
                    lds[yout + q * 32] = w;
                }
            }
            __syncthreads();

            // ---- E3: YX ring update + emit x=a-4; land prefetch ----
            {
                float tI = lds[TB + tid];
                float tJ = lds[TB + 256 + tid];
                float wI = lds[WB + tid];
                float wJ = lds[WB + 256 + tid];
                float vI = lds[vHiI] - lds[vLoI];
                float vJ = lds[vHiI + ZD_V] - lds[vLoI + ZD_V];
                if (a == a0) { vI = 0.f; vJ = 0.f; wI = 0.f; wJ = 0.f; }
                const int p1 = (p + 1) & 7;      // compile-time
                float hdxI = tI - Tr[0][p1];
                float hdxJ = tJ - Tr[1][p1];
                Sdy[0] += vI - Vr[0][p1]; Vr[0][p] = vI;
                Sdy[1] += vJ - Vr[1][p1]; Vr[1][p] = vJ;
                Sdz[0] += wI - Wr[0][p1]; Wr[0][p] = wI;
                Sdz[1] += wJ - Wr[1][p1]; Wr[1][p] = wJ;
                Tr[0][p] = tI; Tr[1][p] = tJ;
                if (p == 0) {
                    if (a == 0) {   // seed clamped prefix T[0] for x=0,1,2
                        Tr[0][5] = tI; Tr[0][6] = tI; Tr[0][7] = tI;
                        Tr[1][5] = tJ; Tr[1][6] = tJ; Tr[1][7] = tJ;
                    }
                }
                if (a >= s0 + 4) {
                    float cross = fabsf(hdxI * hdxJ + Sdy[0] * Sdy[1] + Sdz[0] * Sdz[1]) + 0.01f;
                    float dI = hdxI * hdxI + Sdy[0] * Sdy[0] + Sdz[0] * Sdz[0] + 0.01f;
                    float dJ = hdxJ * hdxJ + Sdy[1] * Sdy[1] + Sdz[1] * Sdz[1] + 0.01f;
                    float val = cross * rsqrtf(dI * dJ);
                    if (okyz) acc += val;
                }
            }
            if (dof) {
#pragma unroll
                for (int k = 0; k < 5; ++k) lds[lof[k]] = okl[k] ? pf[k] : 0.f;
            }
            __syncthreads();
        }
    }

    // ---- register-only tail (seg 7): x = 156,157,158 ----
    if (seg == 7) {
#pragma unroll
        for (int t = 0; t < 3; ++t) {
            const int sl = t + 1;                // planes 153,154,155
            float hdxI = Tr[0][7] - Tr[0][sl];   // T[159] - T[x-3]
            float hdxJ = Tr[1][7] - Tr[1][sl];
            Sdy[0] -= Vr[0][sl]; Sdy[1] -= Vr[1][sl];
            Sdz[0] -= Wr[0][sl]; Sdz[1] -= Wr[1][sl];
            float cross = fabsf(hdxI * hdxJ + Sdy[0] * Sdy[1] + Sdz[0] * Sdz[1]) + 0.01f;
            float dI = hdxI * hdxI + Sdy[0] * Sdy[0] + Sdz[0] * Sdz[0] + 0.01f;
            float dJ = hdxJ * hdxJ + Sdy[1] * Sdy[1] + Sdz[1] * Sdz[1] + 0.01f;
            float val = cross * rsqrtf(dI * dJ);
            if (okyz) acc += val;
        }
    }

    // ---- block reduce + atomic ----
#pragma unroll
    for (int off = 32; off > 0; off >>= 1) acc += __shfl_down(acc, off, 64);
    __syncthreads();
    if ((tid & 63) == 0) lds[tid >> 6] = acc;
    __syncthreads();
    if (tid == 0)
        atomicAdd(out, (lds[0] + lds[1] + lds[2] + lds[3]) * NVOX_INV);
}

extern "C" void kernel_launch(void* const* d_in, const int* in_sizes, int n_in,
                              void* d_out, int out_size, void* d_ws, size_t ws_size,
                              hipStream_t stream) {
    const float* Ii = (const float*)d_in[0];
    const float* Ji = (const float*)d_in[1];
    float* out = (float*)d_out;
    hipMemsetAsync(d_out, 0, sizeof(float) * (out_size > 0 ? out_size : 1), stream);
    dim3 grid(5, 24, 16);   // z-tiles(32) x y-tiles(8) x (8 x-segments * 2 batches)
    grad_sim_tele<<<grid, dim3(256), 0, stream>>>(Ii, Ji, out);
}